// Round 1
// 1645.329 us; speedup vs baseline: 1.7686x; 1.7686x over previous
//
#include <hip/hip_runtime.h>
#include <hip/hip_bf16.h>
#include <cstdint>

// LSTM (relu activations), B=128 T=256 F=4 H=1024, gate order i,f,g,o.
// Persistent kernel: 256 WGs = 4 row-blocks (32 rows) x 64 hidden-blocks (16 units).
// U slice held as bf16 MFMA B-fragments in VGPRs for all 256 steps.
//
// v2 changes vs 2835us baseline:
//  * h exchange now goes through a bf16 buffer in d_ws (fresh address per step,
//    flag-gated): consumers load MFMA A-fragments directly as short8 (half the
//    bytes, no pack8 VALU). fp32 out[] stores become plain cached writebacks
//    (nothing reads them in-kernel) -> off the critical ack path.
//  * per-WAVE flags: producer wave publishes after its own s_waitcnt vmcnt(0)
//    (no WG barrier around the flag); consumer wave polls only the 64
//    (producer-WG x wave) flags covering its own K slice.
//  * zpart double-buffered with conflict-free layout [blk][q][n][v]:
//    b128 contiguous writes, 2-way (free) reads, ONE __syncthreads per step.
// Fallback template<0>: fp32 exchange through out[] (sc1) if ws too small.

#define B_SZ   128
#define T_SZ   256
#define H_SZ   1024
#define G_SZ   4096   // 4*H

typedef __attribute__((ext_vector_type(8))) short short8;
typedef __attribute__((ext_vector_type(4))) float f32x4;

__device__ __forceinline__ short f2bf(float f) {
    union { float f; unsigned u; } a; a.f = f;
    unsigned r = a.u + 0x7fffu + ((a.u >> 16) & 1u);   // RNE
    return (short)(r >> 16);
}

__device__ __forceinline__ float sigmoidf_(float x) {
    return 1.0f / (1.0f + __expf(-x));
}

// 8 fp32 -> short8 bf16 (round half-up via +0x8000, pack hi16 pairs with v_perm)
__device__ __forceinline__ short8 pack8(f32x4 a, f32x4 b) {
    union { f32x4 v; unsigned u[4]; } ua, ub; ua.v = a; ub.v = b;
    union { short8 s; unsigned d[4]; } r;
    r.d[0] = __builtin_amdgcn_perm(ua.u[1] + 0x8000u, ua.u[0] + 0x8000u, 0x07060302u);
    r.d[1] = __builtin_amdgcn_perm(ua.u[3] + 0x8000u, ua.u[2] + 0x8000u, 0x07060302u);
    r.d[2] = __builtin_amdgcn_perm(ub.u[1] + 0x8000u, ub.u[0] + 0x8000u, 0x07060302u);
    r.d[3] = __builtin_amdgcn_perm(ub.u[3] + 0x8000u, ub.u[2] + 0x8000u, 0x07060302u);
    return r.s;
}

template<int BF16EX>
__global__ __launch_bounds__(256, 1)
void lstm_persistent(const float* __restrict__ x, const float* __restrict__ W,
                     const float* __restrict__ U, const float* __restrict__ bias,
                     float* __restrict__ out, unsigned* __restrict__ flags,
                     short* __restrict__ ex)
{
    __shared__ __align__(16) char smem[65536];
    short* Ust = (short*)smem;            // init staging: [256 k][64 cols] bf16
    float* zpA = (float*)smem;            // step partials, buffer 0 (32 KB)
    float* zpB = (float*)(smem + 32768);  // buffer 1

    const int tid  = threadIdx.x;
    const int bid  = blockIdx.x;
    const int rb   = bid >> 6;    // row block 0..3  (rows rb*32 .. +32)
    const int jb   = bid & 63;    // hidden block 0..63 (units jb*16 .. +16)
    const int w    = tid >> 6;    // wave 0..3 -> K slice [w*256, w*256+256)
    const int lane = tid & 63;
    const int q    = lane >> 4;   // quad 0..3
    const int n    = lane & 15;

    // ---------- init: build persistent B fragments from U (fp32 -> bf16) ----------
    short8 bfrag[8][4];           // [kk (32-k chunk within wave slice)][gate]
    for (int kc = 0; kc < 4; ++kc) {
        const int kbase = kc * 256;
        for (int i = tid; i < 256 * 64; i += 256) {
            int k = i >> 6, col = i & 63;
            int gcol = (col >> 4) * 1024 + jb * 16 + (col & 15);
            Ust[k * 64 + col] = f2bf(U[(size_t)(kbase + k) * G_SZ + gcol]);
        }
        __syncthreads();
        if (w == kc) {
            #pragma unroll
            for (int kk = 0; kk < 8; ++kk) {
                #pragma unroll
                for (int g = 0; g < 4; ++g) {
                    short8 bb;
                    #pragma unroll
                    for (int jj = 0; jj < 8; ++jj)
                        bb[jj] = Ust[(kk * 32 + q * 8 + jj) * 64 + g * 16 + n];
                    bfrag[kk][g] = bb;
                }
            }
        }
        __syncthreads();
    }

    // ---------- per-thread epilogue constants ----------
    const int row_l  = tid >> 4;          // 0..15
    const int hid_l  = tid & 15;
    const int hid_g  = jb * 16 + hid_l;
    const int row_g0 = rb * 32 + row_l;   // pair 0 (mt=0)
    const int row_g1 = row_g0 + 16;       // pair 1 (mt=1)
    const int qr = row_l >> 2, vr = row_l & 3;
    float Wr[4][4], br[4];
    #pragma unroll
    for (int g = 0; g < 4; ++g) {
        br[g] = bias[g * 1024 + hid_g];
        #pragma unroll
        for (int f = 0; f < 4; ++f)
            Wr[g][f] = W[(size_t)f * G_SZ + g * 1024 + hid_g];
    }
    float c0 = 0.f, c1 = 0.f;

    const int arow0 = rb * 32 + n;        // A-frag rows (mt 0/1 add 0/16)
    const int krow  = w * 256 + q * 8;
    // per-wave flags: flags[rb*256 + jb*4 + wave] = #steps produced by that wave
    const unsigned* pollp = flags + rb * 256 + w * 64 + lane;   // 64 producer-waves of my K slice
    unsigned* pubp = flags + rb * 256 + jb * 4 + w;

    // ---------- time loop ----------
    for (int t = 0; t < T_SZ; ++t) {
        // x inputs (independent of h; issue early)
        f32x4 xv0 = *(const f32x4*)(x + ((size_t)row_g0 * T_SZ + t) * 4);
        f32x4 xv1 = *(const f32x4*)(x + ((size_t)row_g1 * T_SZ + t) * 4);

        // A fragments: h_{t-1}
        short8 af[8][2];
        if (t == 0) {
            short8 z = {};
            #pragma unroll
            for (int kk = 0; kk < 8; ++kk) { af[kk][0] = z; af[kk][1] = z; }
        } else {
            // per-wave poll: wait until the 64 producer-waves covering my K slice
            // have published step t (value == number of steps produced)
            for (;;) {
                unsigned v = __hip_atomic_load(pollp, __ATOMIC_RELAXED,
                                               __HIP_MEMORY_SCOPE_AGENT);
                if (__all((int)(v >= (unsigned)t))) break;
                __builtin_amdgcn_s_sleep(2);
            }
            __atomic_signal_fence(__ATOMIC_ACQUIRE);  // compiler-only ordering

            if (BF16EX) {
                #pragma unroll
                for (int kk = 0; kk < 8; ++kk) {
                    #pragma unroll
                    for (int mt = 0; mt < 2; ++mt) {
                        const short* p = ex +
                            ((size_t)(arow0 + mt * 16) * T_SZ + (t - 1)) * H_SZ +
                            krow + kk * 32;
                        af[kk][mt] = *(const short8*)p;
                    }
                }
            } else {
                #pragma unroll
                for (int kk = 0; kk < 8; ++kk) {
                    #pragma unroll
                    for (int mt = 0; mt < 2; ++mt) {
                        const float* p = out +
                            ((size_t)(arow0 + mt * 16) * T_SZ + (t - 1)) * H_SZ +
                            krow + kk * 32;
                        f32x4 lo = *(const f32x4*)p;
                        f32x4 hi = *(const f32x4*)(p + 4);
                        af[kk][mt] = pack8(lo, hi);
                    }
                }
            }
        }

        f32x4 acc[2][4];
        #pragma unroll
        for (int mt = 0; mt < 2; ++mt)
            #pragma unroll
            for (int g = 0; g < 4; ++g)
                acc[mt][g] = (f32x4){0.f, 0.f, 0.f, 0.f};

        #pragma unroll
        for (int kk = 0; kk < 8; ++kk)
            #pragma unroll
            for (int mt = 0; mt < 2; ++mt)
                #pragma unroll
                for (int g = 0; g < 4; ++g)
                    acc[mt][g] = __builtin_amdgcn_mfma_f32_16x16x32_bf16(
                        af[kk][mt], bfrag[kk][g], acc[mt][g], 0, 0, 0);

        // K-split partials -> LDS, layout [blk][q][n][v]: contiguous b128 writes
        // (conflict-free), 2-way (free) scalar reads. Double-buffered on t&1.
        float* zp = (t & 1) ? zpB : zpA;
        #pragma unroll
        for (int mt = 0; mt < 2; ++mt)
            #pragma unroll
            for (int g = 0; g < 4; ++g)
                *(f32x4*)&zp[(((w * 2 + mt) * 4 + g) * 4 + q) * 64 + n * 4] =
                    acc[mt][g];
        __syncthreads();   // single barrier per step (write -> read, dbuf'd)

        // ---------- epilogue: sum partials, add x*W+b, gates, state update ----------
        float hn0, hn1;
        {
            float z[4];
            #pragma unroll
            for (int g = 0; g < 4; ++g) {
                float s = br[g];
                #pragma unroll
                for (int ww = 0; ww < 4; ++ww)
                    s += zp[(((ww * 2 + 0) * 4 + g) * 4 + qr) * 64 + hid_l * 4 + vr];
                s += xv0[0] * Wr[g][0] + xv0[1] * Wr[g][1] +
                     xv0[2] * Wr[g][2] + xv0[3] * Wr[g][3];
                z[g] = s;
            }
            float ig = sigmoidf_(z[0]), fg = sigmoidf_(z[1]);
            float gg = fmaxf(z[2], 0.f), og = sigmoidf_(z[3]);
            c0 = fg * c0 + ig * gg;
            hn0 = og * fmaxf(c0, 0.f);
        }
        {
            float z[4];
            #pragma unroll
            for (int g = 0; g < 4; ++g) {
                float s = br[g];
                #pragma unroll
                for (int ww = 0; ww < 4; ++ww)
                    s += zp[(((ww * 2 + 1) * 4 + g) * 4 + qr) * 64 + hid_l * 4 + vr];
                s += xv1[0] * Wr[g][0] + xv1[1] * Wr[g][1] +
                     xv1[2] * Wr[g][2] + xv1[3] * Wr[g][3];
                z[g] = s;
            }
            float ig = sigmoidf_(z[0]), fg = sigmoidf_(z[1]);
            float gg = fmaxf(z[2], 0.f), og = sigmoidf_(z[3]);
            c1 = fg * c1 + ig * gg;
            hn1 = og * fmaxf(c1, 0.f);
        }

        if (BF16EX) {
            // bf16 exchange: pair lanes pack 2 units -> u32, sc1 write-through.
            float o0 = __shfl_down(hn0, 1);
            float o1 = __shfl_down(hn1, 1);
            if ((hid_l & 1) == 0) {
                unsigned w0 = (unsigned)(unsigned short)f2bf(hn0) |
                              ((unsigned)(unsigned short)f2bf(o0) << 16);
                unsigned w1 = (unsigned)(unsigned short)f2bf(hn1) |
                              ((unsigned)(unsigned short)f2bf(o1) << 16);
                __hip_atomic_store(
                    (unsigned*)&ex[((size_t)row_g0 * T_SZ + t) * H_SZ + hid_g],
                    w0, __ATOMIC_RELAXED, __HIP_MEMORY_SCOPE_AGENT);
                __hip_atomic_store(
                    (unsigned*)&ex[((size_t)row_g1 * T_SZ + t) * H_SZ + hid_g],
                    w1, __ATOMIC_RELAXED, __HIP_MEMORY_SCOPE_AGENT);
            }
            // fp32 output: plain cached writeback, nothing reads it in-kernel
            out[((size_t)row_g0 * T_SZ + t) * H_SZ + hid_g] = hn0;
            out[((size_t)row_g1 * T_SZ + t) * H_SZ + hid_g] = hn1;
        } else {
            __hip_atomic_store((unsigned*)&out[((size_t)row_g0 * T_SZ + t) * H_SZ + hid_g],
                               __float_as_uint(hn0), __ATOMIC_RELAXED,
                               __HIP_MEMORY_SCOPE_AGENT);
            __hip_atomic_store((unsigned*)&out[((size_t)row_g1 * T_SZ + t) * H_SZ + hid_g],
                               __float_as_uint(hn1), __ATOMIC_RELAXED,
                               __HIP_MEMORY_SCOPE_AGENT);
        }

        if (t == T_SZ - 1) {
            float* hlast = out + (size_t)B_SZ * T_SZ * H_SZ;
            float* clast = hlast + (size_t)B_SZ * H_SZ;
            hlast[(size_t)row_g0 * H_SZ + hid_g] = hn0;
            hlast[(size_t)row_g1 * H_SZ + hid_g] = hn1;
            clast[(size_t)row_g0 * H_SZ + hid_g] = c0;
            clast[(size_t)row_g1 * H_SZ + hid_g] = c1;
        } else {
            // per-wave publish: my h stores acked (vmcnt 0) -> flag = t+1.
            asm volatile("s_waitcnt vmcnt(0)" ::: "memory");
            if (lane == 0)
                __hip_atomic_store(pubp, (unsigned)(t + 1),
                                   __ATOMIC_RELAXED, __HIP_MEMORY_SCOPE_AGENT);
        }
    }
}

extern "C" void kernel_launch(void* const* d_in, const int* in_sizes, int n_in,
                              void* d_out, int out_size, void* d_ws, size_t ws_size,
                              hipStream_t stream) {
    const float* x    = (const float*)d_in[0];  // [128][256][4]
    const float* W    = (const float*)d_in[1];  // [4][4096]
    const float* U    = (const float*)d_in[2];  // [1024][4096]
    const float* bias = (const float*)d_in[3];  // [4096]
    float* out = (float*)d_out;                 // [128][256][1024] ++ h_last ++ c_last

    unsigned* flags = (unsigned*)d_ws;          // [4 rb][64 jb][4 wave] step flags
    short* ex = (short*)((char*)d_ws + 4096);   // bf16 h exchange [128][256][1024]

    // zero the flags (ws is poisoned 0xAA before every timed launch)
    hipMemsetAsync(d_ws, 0, 4096, stream);

    const size_t need = 4096 + (size_t)B_SZ * T_SZ * H_SZ * sizeof(short);
    if (ws_size >= need) {
        hipLaunchKernelGGL((lstm_persistent<1>), dim3(256), dim3(256), 0, stream,
                           x, W, U, bias, out, flags, ex);
    } else {
        hipLaunchKernelGGL((lstm_persistent<0>), dim3(256), dim3(256), 0, stream,
                           x, W, U, bias, out, flags, ex);
    }
}